// Round 1
// 584.591 us; speedup vs baseline: 1.6822x; 1.6822x over previous
//
#include <hip/hip_runtime.h>

#define LEAK 0.333f
#define BN_EPS 1e-4f

typedef __fp16 h2 __attribute__((ext_vector_type(2)));
typedef __fp16 h8 __attribute__((ext_vector_type(8)));
typedef float  f4 __attribute__((ext_vector_type(4)));

union H8 { h2 p[4]; h8 v; };

// ---------------------------------------------------------------------------
// fill: table[out_idx[i]*4 + kern_idx[i]] = i   (unique slots -> plain stores)
// ---------------------------------------------------------------------------
__global__ __launch_bounds__(256) void fill_table_kernel(
    const int* __restrict__ out_idx, const int* __restrict__ kern_idx,
    int* __restrict__ table, int n_in)
{
    const int i = blockIdx.x * 256 + threadIdx.x;
    if (i < n_in) {
        table[out_idx[i] * 4 + kern_idx[i]] = i;
    }
}

// ---------------------------------------------------------------------------
// MFMA gather conv + fused BN statistics
// one wave per 16-output-row tile; 16x16x32 f16 MFMA, N=64 via 4 n-tiles
//   A frag: lane holds row (lane&15), k-slice (lane>>4)*8..+7  (per slot)
//   B frag: lane holds col (lane&15)+n*16, same k enumeration  -> any
//           within-lane k permutation cancels (k fully summed)
//   C/D   : col = lane&15, row = (lane>>4)*4 + reg   [HW-verified layout]
// ---------------------------------------------------------------------------
__global__ __launch_bounds__(256, 2) void gather_conv_kernel(
    const float* __restrict__ feat, const float* __restrict__ weight,
    const int4* __restrict__ table, float* __restrict__ out,
    float* __restrict__ stats, int n_out)
{
    const int lane = threadIdx.x & 63;
    const int wv   = threadIdx.x >> 6;
    const int c    = lane & 15;   // A row within tile / B,C col within n-tile
    const int g    = lane >> 4;   // k-group (and C row group)
    const int g8   = g * 8;

    // ---- B fragments: bw[slot][ntile] = W[slot][k = g8..g8+7][col = n*16+c]
    H8 bw[4][4];
#pragma unroll
    for (int s = 0; s < 4; ++s)
#pragma unroll
        for (int n = 0; n < 4; ++n)
#pragma unroll
            for (int e = 0; e < 4; ++e) {
                const int k0 = g8 + 2 * e;
                bw[s][n].p[e] = __builtin_amdgcn_cvt_pkrtz(
                    weight[(s * 32 + k0    ) * 64 + n * 16 + c],
                    weight[(s * 32 + k0 + 1) * 64 + n * 16 + c]);
            }

    float sv[4] = {0.f, 0.f, 0.f, 0.f};   // per-column running sum
    float qv[4] = {0.f, 0.f, 0.f, 0.f};   // per-column running sum of squares

    const int ntiles  = (n_out + 15) >> 4;
    const int tstride = gridDim.x * 4;
    int t = blockIdx.x * 4 + wv;

    int4 sl = make_int4(-1, -1, -1, -1);
    if (t < ntiles) {
        const int row = t * 16 + c;
        if (row < n_out) sl = table[row];
    }

    for (; t < ntiles; t += tstride) {
        // ---- prefetch next tile's table entry (hide one memory latency)
        const int tn = t + tstride;
        int4 sln = make_int4(-1, -1, -1, -1);
        if (tn < ntiles) {
            const int rown = tn * 16 + c;
            if (rown < n_out) sln = table[rown];
        }

        // ---- gather A rows: per lane 2x float4 at k-offset g8, predicated
        f4 va[4][2];
#pragma unroll
        for (int s = 0; s < 4; ++s) { va[s][0] = 0.f; va[s][1] = 0.f; }
        const int si[4] = {sl.x, sl.y, sl.z, sl.w};
#pragma unroll
        for (int s = 0; s < 4; ++s) {
            if (si[s] >= 0) {
                const float* p = feat + (size_t)si[s] * 32 + g8;
                va[s][0] = *(const f4*)p;
                va[s][1] = *(const f4*)(p + 4);
            }
        }

        // ---- fp32 -> fp16 A fragments (same enumeration as B)
        H8 af[4];
#pragma unroll
        for (int s = 0; s < 4; ++s) {
            af[s].p[0] = __builtin_amdgcn_cvt_pkrtz(va[s][0].x, va[s][0].y);
            af[s].p[1] = __builtin_amdgcn_cvt_pkrtz(va[s][0].z, va[s][0].w);
            af[s].p[2] = __builtin_amdgcn_cvt_pkrtz(va[s][1].x, va[s][1].y);
            af[s].p[3] = __builtin_amdgcn_cvt_pkrtz(va[s][1].z, va[s][1].w);
        }

        // ---- 16 MFMAs: 4 K-steps (slots) x 4 N-tiles
        f4 acc[4];
#pragma unroll
        for (int n = 0; n < 4; ++n) acc[n] = 0.f;
#pragma unroll
        for (int s = 0; s < 4; ++s)
#pragma unroll
            for (int n = 0; n < 4; ++n)
                acc[n] = __builtin_amdgcn_mfma_f32_16x16x32_f16(
                    af[s].v, bw[s][n].v, acc[n], 0, 0, 0);

        // ---- store + stats: row = t*16 + g*4 + r, col = n*16 + c
        const int rbase = t * 16 + g * 4;
#pragma unroll
        for (int r = 0; r < 4; ++r) {
            const int ro = rbase + r;
            if (ro < n_out) {
                float* po = out + (size_t)ro * 64 + c;
#pragma unroll
                for (int n = 0; n < 4; ++n) po[n * 16] = acc[n][r];
            }
#pragma unroll
            for (int n = 0; n < 4; ++n) {       // OOB rows contribute exact 0
                sv[n] += acc[n][r];
                qv[n] = fmaf(acc[n][r], acc[n][r], qv[n]);
            }
        }
        sl = sln;
    }

    // ---- column sums: fold the 4 k-groups (lanes c, c+16, c+32, c+48)
#pragma unroll
    for (int n = 0; n < 4; ++n) {
        sv[n] += __shfl_xor(sv[n], 16);
        sv[n] += __shfl_xor(sv[n], 32);
        qv[n] += __shfl_xor(qv[n], 16);
        qv[n] += __shfl_xor(qv[n], 32);
    }

    __shared__ float ls[4][64];
    __shared__ float lq[4][64];
    if (lane < 16) {
#pragma unroll
        for (int n = 0; n < 4; ++n) {
            ls[wv][n * 16 + lane] = sv[n];
            lq[wv][n * 16 + lane] = qv[n];
        }
    }
    __syncthreads();
    if (wv == 0) {
        float ts = ls[0][lane] + ls[1][lane] + ls[2][lane] + ls[3][lane];
        float tq = lq[0][lane] + lq[1][lane] + lq[2][lane] + lq[3][lane];
        atomicAdd(&stats[lane], ts);
        atomicAdd(&stats[64 + lane], tq);
    }
}

// ---------------------------------------------------------------------------
__global__ void finalize_kernel(float* __restrict__ stats,
                                const float* __restrict__ gamma,
                                const float* __restrict__ beta, float inv_n)
{
    const int j = threadIdx.x;  // 64 threads
    float mean = stats[j] * inv_n;
    float var  = fmaf(-mean, mean, stats[64 + j] * inv_n);
    var = fmaxf(var, 0.f);
    float scale = gamma[j] * rsqrtf(var + BN_EPS);
    stats[128 + j] = scale;
    stats[192 + j] = beta[j] - mean * scale;
}

__global__ __launch_bounds__(256) void apply_kernel(
    float* __restrict__ out, const float* __restrict__ stats, int n4)
{
    __shared__ float sscale[64];
    __shared__ float sshift[64];
    if (threadIdx.x < 64) {
        sscale[threadIdx.x] = stats[128 + threadIdx.x];
        sshift[threadIdx.x] = stats[192 + threadIdx.x];
    }
    __syncthreads();
    const int idx = blockIdx.x * blockDim.x + threadIdx.x;
    const int stride = gridDim.x * blockDim.x;
    float4* o4 = (float4*)out;
    for (int i = idx; i < n4; i += stride) {
        const int cb = (i * 4) & 63;  // stride*4 % 64 == 0 -> fixed per thread
        float4 v = o4[i];
        v.x = fmaf(v.x, sscale[cb + 0], sshift[cb + 0]);
        v.y = fmaf(v.y, sscale[cb + 1], sshift[cb + 1]);
        v.z = fmaf(v.z, sscale[cb + 2], sshift[cb + 2]);
        v.w = fmaf(v.w, sscale[cb + 3], sshift[cb + 3]);
        v.x = v.x > 0.f ? v.x : LEAK * v.x;
        v.y = v.y > 0.f ? v.y : LEAK * v.y;
        v.z = v.z > 0.f ? v.z : LEAK * v.z;
        v.w = v.w > 0.f ? v.w : LEAK * v.w;
        o4[i] = v;
    }
}

// ---------------------------------------------------------------------------
extern "C" void kernel_launch(void* const* d_in, const int* in_sizes, int n_in,
                              void* d_out, int out_size, void* d_ws, size_t ws_size,
                              hipStream_t stream)
{
    // Inputs: 0=features 1=weight 2=bias(cancels in BN) 3=gamma 4=beta
    //         5=out_idx 6=kern_idx 7=n_out(scalar, unused: out_size/64)
    const float* feat     = (const float*)d_in[0];
    const float* weight   = (const float*)d_in[1];
    const float* gamma    = (const float*)d_in[3];
    const float* beta     = (const float*)d_in[4];
    const int*   out_idx  = (const int*)d_in[5];
    const int*   kern_idx = (const int*)d_in[6];
    const int n_active = in_sizes[5];
    const int n_out    = out_size / 64;
    float* out   = (float*)d_out;
    float* stats = (float*)d_ws;                       // 256 floats
    int*   table = (int*)((char*)d_ws + 1024);         // n_out*4 ints

    (void)hipMemsetAsync(stats, 0, 512, stream);       // sums + sumsqs
    (void)hipMemsetAsync(table, 0xFF, (size_t)n_out * 4 * sizeof(int), stream);  // -1

    fill_table_kernel<<<(n_active + 255) / 256, 256, 0, stream>>>(
        out_idx, kern_idx, table, n_active);
    gather_conv_kernel<<<2048, 256, 0, stream>>>(
        feat, weight, (const int4*)table, out, stats, n_out);
    finalize_kernel<<<1, 64, 0, stream>>>(stats, gamma, beta, 1.0f / (float)n_out);
    apply_kernel<<<2048, 256, 0, stream>>>(out, stats, out_size / 4);
}

// Round 2
// 549.412 us; speedup vs baseline: 1.7899x; 1.0640x over previous
//
#include <hip/hip_runtime.h>

#define LEAK 0.333f
#define BN_EPS 1e-4f

typedef __fp16 h2 __attribute__((ext_vector_type(2)));
typedef __fp16 h8 __attribute__((ext_vector_type(8)));
typedef float  f4 __attribute__((ext_vector_type(4)));

union H8 { h2 p[4]; h8 v; };

// ---------------------------------------------------------------------------
// fill: table[out_idx[i]*4 + kern_idx[i]] = i   (unique slots -> plain stores)
// ---------------------------------------------------------------------------
__global__ __launch_bounds__(256) void fill_table_kernel(
    const int* __restrict__ out_idx, const int* __restrict__ kern_idx,
    int* __restrict__ table, int n_in)
{
    const int i = blockIdx.x * 256 + threadIdx.x;
    if (i < n_in) {
        table[out_idx[i] * 4 + kern_idx[i]] = i;
    }
}

// ---------------------------------------------------------------------------
// MFMA gather conv, two passes sharing one body:
//   APPLY=false : conv -> BN statistics only (no output write)
//   APPLY=true  : conv recomputed (bit-identical) -> y=scale*acc+shift,
//                 LeakyReLU, single coalesced store of the final result
// feat (192 MB) is LLC-resident, so the recompute read is nearly free vs
// storing raw conv out (266 MB) and re-reading it (266 MB) in a 3rd pass.
//
// one wave per 16-output-row tile; 16x16x32 f16 MFMA, N=64 via 4 n-tiles
//   A frag: lane holds row (lane&15), k-slice (lane>>4)*8..+7  (per slot)
//   B frag: lane holds col (lane&15)+n*16, same k enumeration  -> any
//           within-lane k permutation cancels (k fully summed)
//   C/D   : col = lane&15, row = (lane>>4)*4 + reg   [HW-verified layout]
// Software pipeline: table entry prefetched 2 tiles ahead, feature rows
// 1 tile ahead, so gather latency hides under cvt+MFMA of current tile.
// ---------------------------------------------------------------------------
template <bool APPLY>
__global__ __launch_bounds__(256, 2) void conv_pass_kernel(
    const float* __restrict__ feat, const float* __restrict__ weight,
    const int4* __restrict__ table, float* __restrict__ out,
    float* __restrict__ stats, int n_out)
{
    const int lane = threadIdx.x & 63;
    const int wv   = threadIdx.x >> 6;
    const int c    = lane & 15;   // A row within tile / B,C col within n-tile
    const int g    = lane >> 4;   // k-group (and C row group)
    const int g8   = g * 8;

    // ---- B fragments: bw[slot][ntile] = W[slot][k = g8..g8+7][col = n*16+c]
    H8 bw[4][4];
#pragma unroll
    for (int s = 0; s < 4; ++s)
#pragma unroll
        for (int n = 0; n < 4; ++n)
#pragma unroll
            for (int e = 0; e < 4; ++e) {
                const int k0 = g8 + 2 * e;
                bw[s][n].p[e] = __builtin_amdgcn_cvt_pkrtz(
                    weight[(s * 32 + k0    ) * 64 + n * 16 + c],
                    weight[(s * 32 + k0 + 1) * 64 + n * 16 + c]);
            }

    // ---- BN affine params (apply pass only); channel = n*16 + c
    float scl[4], sft[4];
    if (APPLY) {
#pragma unroll
        for (int n = 0; n < 4; ++n) {
            scl[n] = stats[128 + n * 16 + c];
            sft[n] = stats[192 + n * 16 + c];
        }
    }

    float sv[4] = {0.f, 0.f, 0.f, 0.f};   // per-column running sum
    float qv[4] = {0.f, 0.f, 0.f, 0.f};   // per-column running sum of squares

    const int ntiles  = (n_out + 15) >> 4;
    const int tstride = gridDim.x * 4;
    int t = blockIdx.x * 4 + wv;

    int4 sl  = make_int4(-1, -1, -1, -1);
    int4 sl1 = make_int4(-1, -1, -1, -1);
    f4 va[4][2];
#pragma unroll
    for (int s = 0; s < 4; ++s) { va[s][0] = 0.f; va[s][1] = 0.f; }

    if (t < ntiles) {
        const int row = t * 16 + c;
        if (row < n_out) sl = table[row];
        const int si0[4] = {sl.x, sl.y, sl.z, sl.w};
#pragma unroll
        for (int s = 0; s < 4; ++s) {
            if (si0[s] >= 0) {
                const float* p = feat + (size_t)si0[s] * 32 + g8;
                va[s][0] = *(const f4*)p;
                va[s][1] = *(const f4*)(p + 4);
            }
        }
        const int tn = t + tstride;
        if (tn < ntiles) {
            const int rn = tn * 16 + c;
            if (rn < n_out) sl1 = table[rn];
        }
    }

    for (; t < ntiles; t += tstride) {
        const int tn = t + tstride;

        // ---- prefetch table entry two tiles ahead
        int4 sl2 = make_int4(-1, -1, -1, -1);
        const int tn2 = tn + tstride;
        if (tn2 < ntiles) {
            const int rn2 = tn2 * 16 + c;
            if (rn2 < n_out) sl2 = table[rn2];
        }

        // ---- prefetch next tile's A rows (hides HBM latency under compute)
        f4 vb[4][2];
#pragma unroll
        for (int s = 0; s < 4; ++s) { vb[s][0] = 0.f; vb[s][1] = 0.f; }
        if (tn < ntiles) {
            const int si1[4] = {sl1.x, sl1.y, sl1.z, sl1.w};
#pragma unroll
            for (int s = 0; s < 4; ++s) {
                if (si1[s] >= 0) {
                    const float* p = feat + (size_t)si1[s] * 32 + g8;
                    vb[s][0] = *(const f4*)p;
                    vb[s][1] = *(const f4*)(p + 4);
                }
            }
        }

        // ---- fp32 -> fp16 A fragments (same enumeration as B)
        H8 af[4];
#pragma unroll
        for (int s = 0; s < 4; ++s) {
            af[s].p[0] = __builtin_amdgcn_cvt_pkrtz(va[s][0].x, va[s][0].y);
            af[s].p[1] = __builtin_amdgcn_cvt_pkrtz(va[s][0].z, va[s][0].w);
            af[s].p[2] = __builtin_amdgcn_cvt_pkrtz(va[s][1].x, va[s][1].y);
            af[s].p[3] = __builtin_amdgcn_cvt_pkrtz(va[s][1].z, va[s][1].w);
        }

        // ---- 16 MFMAs: 4 K-steps (slots) x 4 N-tiles
        f4 acc[4];
#pragma unroll
        for (int n = 0; n < 4; ++n) acc[n] = 0.f;
#pragma unroll
        for (int s = 0; s < 4; ++s)
#pragma unroll
            for (int n = 0; n < 4; ++n)
                acc[n] = __builtin_amdgcn_mfma_f32_16x16x32_f16(
                    af[s].v, bw[s][n].v, acc[n], 0, 0, 0);

        // ---- stats or fused BN+LeakyReLU store
        const int rbase = t * 16 + g * 4;
#pragma unroll
        for (int r = 0; r < 4; ++r) {
            const int ro = rbase + r;
            if (APPLY) {
                if (ro < n_out) {
                    float* po = out + (size_t)ro * 64 + c;
#pragma unroll
                    for (int n = 0; n < 4; ++n) {
                        float y = fmaf(acc[n][r], scl[n], sft[n]);
                        po[n * 16] = y > 0.f ? y : LEAK * y;
                    }
                }
            } else {
#pragma unroll
                for (int n = 0; n < 4; ++n) {   // OOB rows contribute exact 0
                    sv[n] += acc[n][r];
                    qv[n] = fmaf(acc[n][r], acc[n][r], qv[n]);
                }
            }
        }

        // ---- rotate pipeline registers
#pragma unroll
        for (int s = 0; s < 4; ++s) { va[s][0] = vb[s][0]; va[s][1] = vb[s][1]; }
        sl1 = sl2;
    }

    if constexpr (!APPLY) {
        // ---- column sums: fold the 4 k-groups (lanes c, c+16, c+32, c+48)
#pragma unroll
        for (int n = 0; n < 4; ++n) {
            sv[n] += __shfl_xor(sv[n], 16);
            sv[n] += __shfl_xor(sv[n], 32);
            qv[n] += __shfl_xor(qv[n], 16);
            qv[n] += __shfl_xor(qv[n], 32);
        }

        __shared__ float ls[4][64];
        __shared__ float lq[4][64];
        if (lane < 16) {
#pragma unroll
            for (int n = 0; n < 4; ++n) {
                ls[wv][n * 16 + lane] = sv[n];
                lq[wv][n * 16 + lane] = qv[n];
            }
        }
        __syncthreads();
        if (wv == 0) {
            float ts = ls[0][lane] + ls[1][lane] + ls[2][lane] + ls[3][lane];
            float tq = lq[0][lane] + lq[1][lane] + lq[2][lane] + lq[3][lane];
            atomicAdd(&stats[lane], ts);
            atomicAdd(&stats[64 + lane], tq);
        }
    }
}

// ---------------------------------------------------------------------------
__global__ void finalize_kernel(float* __restrict__ stats,
                                const float* __restrict__ gamma,
                                const float* __restrict__ beta, float inv_n)
{
    const int j = threadIdx.x;  // 64 threads
    float mean = stats[j] * inv_n;
    float var  = fmaf(-mean, mean, stats[64 + j] * inv_n);
    var = fmaxf(var, 0.f);
    float scale = gamma[j] * rsqrtf(var + BN_EPS);
    stats[128 + j] = scale;
    stats[192 + j] = beta[j] - mean * scale;
}

// ---------------------------------------------------------------------------
extern "C" void kernel_launch(void* const* d_in, const int* in_sizes, int n_in,
                              void* d_out, int out_size, void* d_ws, size_t ws_size,
                              hipStream_t stream)
{
    // Inputs: 0=features 1=weight 2=bias(cancels in BN) 3=gamma 4=beta
    //         5=out_idx 6=kern_idx 7=n_out(scalar, unused: out_size/64)
    const float* feat     = (const float*)d_in[0];
    const float* weight   = (const float*)d_in[1];
    const float* gamma    = (const float*)d_in[3];
    const float* beta     = (const float*)d_in[4];
    const int*   out_idx  = (const int*)d_in[5];
    const int*   kern_idx = (const int*)d_in[6];
    const int n_active = in_sizes[5];
    const int n_out    = out_size / 64;
    float* out   = (float*)d_out;
    float* stats = (float*)d_ws;                       // 256 floats
    int*   table = (int*)((char*)d_ws + 1024);         // n_out*4 ints

    (void)hipMemsetAsync(stats, 0, 512, stream);       // sums + sumsqs
    (void)hipMemsetAsync(table, 0xFF, (size_t)n_out * 4 * sizeof(int), stream);  // -1

    fill_table_kernel<<<(n_active + 255) / 256, 256, 0, stream>>>(
        out_idx, kern_idx, table, n_active);
    conv_pass_kernel<false><<<2048, 256, 0, stream>>>(
        feat, weight, (const int4*)table, nullptr, stats, n_out);
    finalize_kernel<<<1, 64, 0, stream>>>(stats, gamma, beta, 1.0f / (float)n_out);
    conv_pass_kernel<true><<<2048, 256, 0, stream>>>(
        feat, weight, (const int4*)table, out, stats, n_out);
}